// Round 1
// baseline (565.306 us; speedup 1.0000x reference)
//
#include <hip/hip_runtime.h>

// VQ-VAE quantization: z [16384 x 512] f32, codebook [8192 x 512] f32.
// out = concat(z_st [16384*512] f32, vq_loss [1] f32).
// Strategy: bf16 MFMA GEMM (scores = z @ cb^T) with fused argmin epilogue,
// then gather + loss. Distances use d = ||e||^2 - 2 z.e (row-constant ||z||^2
// dropped; argmin invariant).

#define M_ROWS 16384
#define K_CODES 8192
#define DIM 512
#define BM 128
#define BN 128
#define BK 64
#define NT (K_CODES / BN)   // 64 ktiles
#define OUT0_SIZE (M_ROWS * DIM)

typedef __bf16 bf16x8 __attribute__((ext_vector_type(8)));
typedef float f32x4 __attribute__((ext_vector_type(4)));

__device__ __forceinline__ unsigned short f2bf(float f) {
    unsigned int u = __builtin_bit_cast(unsigned int, f);
    u += 0x7FFFu + ((u >> 16) & 1u);   // RNE; inputs are finite
    return (unsigned short)(u >> 16);
}

// ---- kernel 1: z (f32) -> zb (bf16 bits) -------------------------------
__global__ __launch_bounds__(256) void convert_z(const float* __restrict__ z,
                                                 unsigned short* __restrict__ zb) {
    size_t i = ((size_t)blockIdx.x * 256 + threadIdx.x) * 4;
    float4 v = *(const float4*)(z + i);
    ushort4 o;
    o.x = f2bf(v.x); o.y = f2bf(v.y); o.z = f2bf(v.z); o.w = f2bf(v.w);
    *(ushort4*)(zb + i) = o;
}

// ---- kernel 2: codebook -> bf16 + row norms ----------------------------
__global__ __launch_bounds__(256) void convert_cb(const float* __restrict__ cb,
                                                  unsigned short* __restrict__ cbb,
                                                  float* __restrict__ enorm) {
    __shared__ float red[4];
    int k = blockIdx.x, tid = threadIdx.x;
    float2 v = ((const float2*)(cb + (size_t)k * DIM))[tid];
    ushort2 o; o.x = f2bf(v.x); o.y = f2bf(v.y);
    ((ushort2*)(cbb + (size_t)k * DIM))[tid] = o;
    float p = v.x * v.x + v.y * v.y;
    for (int m = 32; m; m >>= 1) p += __shfl_down(p, m, 64);
    if ((tid & 63) == 0) red[tid >> 6] = p;
    __syncthreads();
    if (tid == 0) enorm[k] = (red[0] + red[1]) + (red[2] + red[3]);
}

// ---- kernel 3: MFMA GEMM + argmin epilogue -----------------------------
__global__ __launch_bounds__(256, 2) void gemm_argmin(
    const unsigned short* __restrict__ zb, const unsigned short* __restrict__ cbb,
    const float* __restrict__ enorm, float* __restrict__ candV, int* __restrict__ candI) {
    __shared__ unsigned short As[BM * BK];   // 16 KB
    __shared__ unsigned short Bs[BN * BK];   // 16 KB
    __shared__ float Es[BN];
    __shared__ float cV[BM][2];
    __shared__ int cI[BM][2];

    const int tid = threadIdx.x;
    const int lane = tid & 63;
    const int w = tid >> 6;
    const int ktile = blockIdx.x;
    const int mtile = blockIdx.y;
    const int mbase = mtile * BM;
    const int nbase = ktile * BN;

    if (tid < BN) Es[tid] = enorm[nbase + tid];

    f32x4 acc[16];
#pragma unroll
    for (int i = 0; i < 16; ++i) acc[i] = (f32x4){0.f, 0.f, 0.f, 0.f};

    const int rA = lane >> 3;           // row offset within 8-row chunk
    const int c8 = (lane & 7) * 8;      // element offset within row
    const int quad = lane >> 4;
    const int l15 = lane & 15;
    const int rw = (w >> 1) * 64;       // wave's row quadrant
    const int cw = (w & 1) * 64;        // wave's col quadrant

    for (int dt = 0; dt < DIM; dt += BK) {
#pragma unroll
        for (int i = 0; i < 4; ++i) {
            int c = w * 4 + i;                       // 1KB chunk id (0..15)
            int row = c * 8 + rA;
            const unsigned short* ga = zb + (size_t)(mbase + row) * DIM + dt + c8;
            const unsigned short* gb = cbb + (size_t)(nbase + row) * DIM + dt + c8;
            unsigned short* la = As + c * 512 + lane * 8;
            unsigned short* lb = Bs + c * 512 + lane * 8;
            __builtin_amdgcn_global_load_lds((const __attribute__((address_space(1))) void*)ga,
                                             (__attribute__((address_space(3))) void*)la, 16, 0, 0);
            __builtin_amdgcn_global_load_lds((const __attribute__((address_space(1))) void*)gb,
                                             (__attribute__((address_space(3))) void*)lb, 16, 0, 0);
        }
        __syncthreads();
#pragma unroll
        for (int s = 0; s < 2; ++s) {
            bf16x8 af[4], bfr[4];
#pragma unroll
            for (int rf = 0; rf < 4; ++rf)
                af[rf] = *(const bf16x8*)(As + (rw + rf * 16 + l15) * BK + s * 32 + quad * 8);
#pragma unroll
            for (int cf = 0; cf < 4; ++cf)
                bfr[cf] = *(const bf16x8*)(Bs + (cw + cf * 16 + l15) * BK + s * 32 + quad * 8);
#pragma unroll
            for (int rf = 0; rf < 4; ++rf)
#pragma unroll
                for (int cf = 0; cf < 4; ++cf)
                    acc[rf * 4 + cf] = __builtin_amdgcn_mfma_f32_16x16x32_bf16(
                        af[rf], bfr[cf], acc[rf * 4 + cf], 0, 0, 0);
        }
        __syncthreads();
    }

    // epilogue: per-row argmin over this tile's 128 cols.
    // C/D layout: col = lane&15, row = quad*4 + reg.
#pragma unroll
    for (int rf = 0; rf < 4; ++rf) {
#pragma unroll
        for (int r = 0; r < 4; ++r) {
            float bv = 3.4e38f; int bi = 0x7fffffff;
#pragma unroll
            for (int cf = 0; cf < 4; ++cf) {
                int col = cw + cf * 16 + l15;
                float dist = Es[col] - 2.0f * acc[rf * 4 + cf][r];
                if (dist < bv) { bv = dist; bi = nbase + col; }  // strict <: lowest idx on tie
            }
#pragma unroll
            for (int m = 1; m < 16; m <<= 1) {
                float ov = __shfl_xor(bv, m, 64);
                int oi = __shfl_xor(bi, m, 64);
                if (ov < bv || (ov == bv && oi < bi)) { bv = ov; bi = oi; }
            }
            if (l15 == 0) {
                int rowT = rw + rf * 16 + quad * 4 + r;
                cV[rowT][w & 1] = bv;
                cI[rowT][w & 1] = bi;
            }
        }
    }
    __syncthreads();
    if (tid < BM) {
        float v0 = cV[tid][0], v1 = cV[tid][1];
        int i0 = cI[tid][0], i1 = cI[tid][1];
        bool take1 = (v1 < v0) || (v1 == v0 && i1 < i0);
        int row = mbase + tid;
        candV[(size_t)row * NT + ktile] = take1 ? v1 : v0;
        candI[(size_t)row * NT + ktile] = take1 ? i1 : i0;
    }
}

// ---- kernel 4: reduce 64 candidates per row -> final index -------------
__global__ __launch_bounds__(256) void reduce_cand(const float* __restrict__ candV,
                                                   const int* __restrict__ candI,
                                                   int* __restrict__ idxOut,
                                                   float* __restrict__ lossSlot) {
    int w = threadIdx.x >> 6, lane = threadIdx.x & 63;
    int row = blockIdx.x * 4 + w;
    float v = candV[(size_t)row * NT + lane];
    int i = candI[(size_t)row * NT + lane];
    for (int m = 1; m < 64; m <<= 1) {
        float ov = __shfl_xor(v, m, 64);
        int oi = __shfl_xor(i, m, 64);
        if (ov < v || (ov == v && oi < i)) { v = ov; i = oi; }
    }
    if (lane == 0) idxOut[row] = i;
    if (blockIdx.x == 0 && threadIdx.x == 0) *lossSlot = 0.f;  // k5 (next launch) accumulates
}

// ---- kernel 5: gather, straight-through output, loss -------------------
__global__ __launch_bounds__(256) void gather_out(const float* __restrict__ z,
                                                  const float* __restrict__ cb,
                                                  const int* __restrict__ idx,
                                                  float* __restrict__ out) {
    __shared__ float red[4];
    int row = blockIdx.x, tid = threadIdx.x;
    int k = idx[row];
    float2 zv = ((const float2*)(z + (size_t)row * DIM))[tid];
    float2 cv = ((const float2*)(cb + (size_t)k * DIM))[tid];
    float dx = cv.x - zv.x, dy = cv.y - zv.y;
    float2 o; o.x = zv.x + dx; o.y = zv.y + dy;   // z + sg(zq - z), reference rounding
    ((float2*)(out + (size_t)row * DIM))[tid] = o;
    float p = dx * dx + dy * dy;
    for (int m = 32; m; m >>= 1) p += __shfl_down(p, m, 64);
    if ((tid & 63) == 0) red[tid >> 6] = p;
    __syncthreads();
    if (tid == 0) {
        float t = (red[0] + red[1]) + (red[2] + red[3]);
        atomicAdd(out + OUT0_SIZE, t * (1.1f / (float)OUT0_SIZE));  // vq_loss = 1.1 * mean
    }
}

extern "C" void kernel_launch(void* const* d_in, const int* in_sizes, int n_in,
                              void* d_out, int out_size, void* d_ws, size_t ws_size,
                              hipStream_t stream) {
    const float* z = (const float*)d_in[0];     // 16*1024*512
    const float* cb = (const float*)d_in[1];    // 8192*512
    float* out = (float*)d_out;                 // 8388608 + 1
    char* ws = (char*)d_ws;

    // ws layout (bytes)
    unsigned short* zb  = (unsigned short*)(ws);              // 16,777,216
    unsigned short* cbb = (unsigned short*)(ws + 16777216);   //  8,388,608
    float* enorm        = (float*)(ws + 25165824);            //     32,768
    float* candV        = (float*)(ws + 25198592);            //  4,194,304
    int*   candI        = (int*)(ws + 29392896);              //  4,194,304
    int*   idxOut       = (int*)(ws + 33587200);              //     65,536

    convert_z<<<8192, 256, 0, stream>>>(z, zb);
    convert_cb<<<8192, 256, 0, stream>>>(cb, cbb, enorm);
    gemm_argmin<<<dim3(NT, M_ROWS / BM), 256, 0, stream>>>(zb, cbb, enorm, candV, candI);
    reduce_cand<<<M_ROWS / 4, 256, 0, stream>>>(candV, candI, idxOut, out + OUT0_SIZE);
    gather_out<<<M_ROWS, 256, 0, stream>>>(z, cb, idxOut, out);
}

// Round 2
// 484.533 us; speedup vs baseline: 1.1667x; 1.1667x over previous
//
#include <hip/hip_runtime.h>

// VQ-VAE quantization: z [16384 x 512] f32, codebook [8192 x 512] f32.
// out = concat(z_st [16384*512] f32, vq_loss [1] f32).
// bf16 MFMA GEMM (scores = z @ cb^T) with fused argmin epilogue, then
// gather + loss. d = ||e||^2 - 2 z.e (row-constant ||z||^2 dropped).
//
// R2: XOR-swizzled LDS layout. Rows are 128 B (= 32 banks), so naive
// fragment reads were 16-way bank-conflicted (5e7 conflict cycles, +12
// cyc/ds_read_b128). LDS chunk j of row r now holds global chunk j^(r&7),
// applied on the global_load_lds source address (LDS dest must stay
// lane-contiguous); fragment reads xor with (row&7) to compensate.

#define M_ROWS 16384
#define K_CODES 8192
#define DIM 512
#define BM 128
#define BN 128
#define BK 64
#define NT (K_CODES / BN)   // 64 ktiles
#define OUT0_SIZE (M_ROWS * DIM)

typedef __bf16 bf16x8 __attribute__((ext_vector_type(8)));
typedef float f32x4 __attribute__((ext_vector_type(4)));

__device__ __forceinline__ unsigned short f2bf(float f) {
    unsigned int u = __builtin_bit_cast(unsigned int, f);
    u += 0x7FFFu + ((u >> 16) & 1u);   // RNE; inputs are finite
    return (unsigned short)(u >> 16);
}

// ---- kernel 1: z (f32) -> zb (bf16 bits) -------------------------------
__global__ __launch_bounds__(256) void convert_z(const float* __restrict__ z,
                                                 unsigned short* __restrict__ zb) {
    size_t i = ((size_t)blockIdx.x * 256 + threadIdx.x) * 4;
    float4 v = *(const float4*)(z + i);
    ushort4 o;
    o.x = f2bf(v.x); o.y = f2bf(v.y); o.z = f2bf(v.z); o.w = f2bf(v.w);
    *(ushort4*)(zb + i) = o;
}

// ---- kernel 2: codebook -> bf16 + row norms ----------------------------
__global__ __launch_bounds__(256) void convert_cb(const float* __restrict__ cb,
                                                  unsigned short* __restrict__ cbb,
                                                  float* __restrict__ enorm) {
    __shared__ float red[4];
    int k = blockIdx.x, tid = threadIdx.x;
    float2 v = ((const float2*)(cb + (size_t)k * DIM))[tid];
    ushort2 o; o.x = f2bf(v.x); o.y = f2bf(v.y);
    ((ushort2*)(cbb + (size_t)k * DIM))[tid] = o;
    float p = v.x * v.x + v.y * v.y;
    for (int m = 32; m; m >>= 1) p += __shfl_down(p, m, 64);
    if ((tid & 63) == 0) red[tid >> 6] = p;
    __syncthreads();
    if (tid == 0) enorm[k] = (red[0] + red[1]) + (red[2] + red[3]);
}

// ---- kernel 3: MFMA GEMM + argmin epilogue -----------------------------
__global__ __launch_bounds__(256, 2) void gemm_argmin(
    const unsigned short* __restrict__ zb, const unsigned short* __restrict__ cbb,
    const float* __restrict__ enorm, float* __restrict__ candV, int* __restrict__ candI) {
    __shared__ unsigned short As[BM * BK];   // 16 KB
    __shared__ unsigned short Bs[BN * BK];   // 16 KB
    __shared__ float Es[BN];
    __shared__ float cV[BM][2];
    __shared__ int cI[BM][2];

    const int tid = threadIdx.x;
    const int lane = tid & 63;
    const int w = tid >> 6;
    const int ktile = blockIdx.x;
    const int mtile = blockIdx.y;
    const int mbase = mtile * BM;
    const int nbase = ktile * BN;

    if (tid < BN) Es[tid] = enorm[nbase + tid];

    f32x4 acc[16];
#pragma unroll
    for (int i = 0; i < 16; ++i) acc[i] = (f32x4){0.f, 0.f, 0.f, 0.f};

    const int rA = lane >> 3;               // row offset within 8-row chunk
    const int jG = ((lane & 7) ^ rA) * 8;   // swizzled global 8-short chunk
    const int quad = lane >> 4;
    const int l15 = lane & 15;
    const int sw = (l15 & 7);               // read-side xor term = row&7
    const int rw = (w >> 1) * 64;           // wave's row quadrant
    const int cw = (w & 1) * 64;            // wave's col quadrant

    for (int dt = 0; dt < DIM; dt += BK) {
#pragma unroll
        for (int i = 0; i < 4; ++i) {
            int c = w * 4 + i;                       // 1KB chunk id (0..15)
            int row = c * 8 + rA;
            const unsigned short* ga = zb + (size_t)(mbase + row) * DIM + dt + jG;
            const unsigned short* gb = cbb + (size_t)(nbase + row) * DIM + dt + jG;
            unsigned short* la = As + c * 512 + lane * 8;
            unsigned short* lb = Bs + c * 512 + lane * 8;
            __builtin_amdgcn_global_load_lds((const __attribute__((address_space(1))) void*)ga,
                                             (__attribute__((address_space(3))) void*)la, 16, 0, 0);
            __builtin_amdgcn_global_load_lds((const __attribute__((address_space(1))) void*)gb,
                                             (__attribute__((address_space(3))) void*)lb, 16, 0, 0);
        }
        __syncthreads();
#pragma unroll
        for (int s = 0; s < 2; ++s) {
            // global chunk wanted: s*4 + quad; LDS chunk = (s*4+quad)^(row&7)
            const int jL = ((s * 4 + quad) ^ sw) * 8;
            bf16x8 af[4], bfr[4];
#pragma unroll
            for (int rf = 0; rf < 4; ++rf)
                af[rf] = *(const bf16x8*)(As + (rw + rf * 16 + l15) * BK + jL);
#pragma unroll
            for (int cf = 0; cf < 4; ++cf)
                bfr[cf] = *(const bf16x8*)(Bs + (cw + cf * 16 + l15) * BK + jL);
#pragma unroll
            for (int rf = 0; rf < 4; ++rf)
#pragma unroll
                for (int cf = 0; cf < 4; ++cf)
                    acc[rf * 4 + cf] = __builtin_amdgcn_mfma_f32_16x16x32_bf16(
                        af[rf], bfr[cf], acc[rf * 4 + cf], 0, 0, 0);
        }
        __syncthreads();
    }

    // epilogue: per-row argmin over this tile's 128 cols.
    // C/D layout: col = lane&15, row = quad*4 + reg.
#pragma unroll
    for (int rf = 0; rf < 4; ++rf) {
#pragma unroll
        for (int r = 0; r < 4; ++r) {
            float bv = 3.4e38f; int bi = 0x7fffffff;
#pragma unroll
            for (int cf = 0; cf < 4; ++cf) {
                int col = cw + cf * 16 + l15;
                float dist = Es[col] - 2.0f * acc[rf * 4 + cf][r];
                if (dist < bv) { bv = dist; bi = nbase + col; }  // strict <: lowest idx on tie
            }
#pragma unroll
            for (int m = 1; m < 16; m <<= 1) {
                float ov = __shfl_xor(bv, m, 64);
                int oi = __shfl_xor(bi, m, 64);
                if (ov < bv || (ov == bv && oi < bi)) { bv = ov; bi = oi; }
            }
            if (l15 == 0) {
                int rowT = rw + rf * 16 + quad * 4 + r;
                cV[rowT][w & 1] = bv;
                cI[rowT][w & 1] = bi;
            }
        }
    }
    __syncthreads();
    if (tid < BM) {
        float v0 = cV[tid][0], v1 = cV[tid][1];
        int i0 = cI[tid][0], i1 = cI[tid][1];
        bool take1 = (v1 < v0) || (v1 == v0 && i1 < i0);
        int row = mbase + tid;
        candV[(size_t)row * NT + ktile] = take1 ? v1 : v0;
        candI[(size_t)row * NT + ktile] = take1 ? i1 : i0;
    }
}

// ---- kernel 4: reduce 64 candidates per row -> final index -------------
__global__ __launch_bounds__(256) void reduce_cand(const float* __restrict__ candV,
                                                   const int* __restrict__ candI,
                                                   int* __restrict__ idxOut,
                                                   float* __restrict__ lossSlot) {
    int w = threadIdx.x >> 6, lane = threadIdx.x & 63;
    int row = blockIdx.x * 4 + w;
    float v = candV[(size_t)row * NT + lane];
    int i = candI[(size_t)row * NT + lane];
    for (int m = 1; m < 64; m <<= 1) {
        float ov = __shfl_xor(v, m, 64);
        int oi = __shfl_xor(i, m, 64);
        if (ov < v || (ov == v && oi < i)) { v = ov; i = oi; }
    }
    if (lane == 0) idxOut[row] = i;
    if (blockIdx.x == 0 && threadIdx.x == 0) *lossSlot = 0.f;  // k5 (next launch) accumulates
}

// ---- kernel 5: gather, straight-through output, loss -------------------
__global__ __launch_bounds__(256) void gather_out(const float* __restrict__ z,
                                                  const float* __restrict__ cb,
                                                  const int* __restrict__ idx,
                                                  float* __restrict__ out) {
    __shared__ float red[4];
    int row = blockIdx.x, tid = threadIdx.x;
    int k = idx[row];
    float2 zv = ((const float2*)(z + (size_t)row * DIM))[tid];
    float2 cv = ((const float2*)(cb + (size_t)k * DIM))[tid];
    float dx = cv.x - zv.x, dy = cv.y - zv.y;
    float2 o; o.x = zv.x + dx; o.y = zv.y + dy;   // z + sg(zq - z), reference rounding
    ((float2*)(out + (size_t)row * DIM))[tid] = o;
    float p = dx * dx + dy * dy;
    for (int m = 32; m; m >>= 1) p += __shfl_down(p, m, 64);
    if ((tid & 63) == 0) red[tid >> 6] = p;
    __syncthreads();
    if (tid == 0) {
        float t = (red[0] + red[1]) + (red[2] + red[3]);
        atomicAdd(out + OUT0_SIZE, t * (1.1f / (float)OUT0_SIZE));  // vq_loss = 1.1 * mean
    }
}

extern "C" void kernel_launch(void* const* d_in, const int* in_sizes, int n_in,
                              void* d_out, int out_size, void* d_ws, size_t ws_size,
                              hipStream_t stream) {
    const float* z = (const float*)d_in[0];     // 16*1024*512
    const float* cb = (const float*)d_in[1];    // 8192*512
    float* out = (float*)d_out;                 // 8388608 + 1
    char* ws = (char*)d_ws;

    // ws layout (bytes)
    unsigned short* zb  = (unsigned short*)(ws);              // 16,777,216
    unsigned short* cbb = (unsigned short*)(ws + 16777216);   //  8,388,608
    float* enorm        = (float*)(ws + 25165824);            //     32,768
    float* candV        = (float*)(ws + 25198592);            //  4,194,304
    int*   candI        = (int*)(ws + 29392896);              //  4,194,304
    int*   idxOut       = (int*)(ws + 33587200);              //     65,536

    convert_z<<<8192, 256, 0, stream>>>(z, zb);
    convert_cb<<<8192, 256, 0, stream>>>(cb, cbb, enorm);
    gemm_argmin<<<dim3(NT, M_ROWS / BM), 256, 0, stream>>>(zb, cbb, enorm, candV, candI);
    reduce_cand<<<M_ROWS / 4, 256, 0, stream>>>(candV, candI, idxOut, out + OUT0_SIZE);
    gather_out<<<M_ROWS, 256, 0, stream>>>(z, cb, idxOut, out);
}

// Round 3
// 294.353 us; speedup vs baseline: 1.9205x; 1.6461x over previous
//
#include <hip/hip_runtime.h>

// VQ-VAE quantization: z [16384 x 512] f32, codebook [8192 x 512] f32.
// out = concat(z_st [16384*512] f32, vq_loss [1] f32).
// bf16 MFMA GEMM (scores = z @ cb^T) with fused argmin epilogue, then
// gather + loss. d = ||e||^2 - 2 z.e (row-constant ||z||^2 dropped).
//
// R2: XOR-swizzled LDS (bank conflicts 5e7 -> ~0), gemm 280 -> ~200 us.
// R3: gather_out was atomic-serialization-bound (16384 same-address
// atomicAdds ~= 212 us). Now grid-stride, 1024 blocks, register loss
// accumulation, ONE atomic per block (1024 total).

#define M_ROWS 16384
#define K_CODES 8192
#define DIM 512
#define BM 128
#define BN 128
#define BK 64
#define NT (K_CODES / BN)   // 64 ktiles
#define OUT0_SIZE (M_ROWS * DIM)
#define GB_BLOCKS 1024

typedef __bf16 bf16x8 __attribute__((ext_vector_type(8)));
typedef float f32x4 __attribute__((ext_vector_type(4)));

__device__ __forceinline__ unsigned short f2bf(float f) {
    unsigned int u = __builtin_bit_cast(unsigned int, f);
    u += 0x7FFFu + ((u >> 16) & 1u);   // RNE; inputs are finite
    return (unsigned short)(u >> 16);
}

// ---- kernel 1: z (f32) -> zb (bf16 bits) -------------------------------
__global__ __launch_bounds__(256) void convert_z(const float* __restrict__ z,
                                                 unsigned short* __restrict__ zb) {
    size_t i = ((size_t)blockIdx.x * 256 + threadIdx.x) * 4;
    float4 v = *(const float4*)(z + i);
    ushort4 o;
    o.x = f2bf(v.x); o.y = f2bf(v.y); o.z = f2bf(v.z); o.w = f2bf(v.w);
    *(ushort4*)(zb + i) = o;
}

// ---- kernel 2: codebook -> bf16 + row norms ----------------------------
__global__ __launch_bounds__(256) void convert_cb(const float* __restrict__ cb,
                                                  unsigned short* __restrict__ cbb,
                                                  float* __restrict__ enorm) {
    __shared__ float red[4];
    int k = blockIdx.x, tid = threadIdx.x;
    float2 v = ((const float2*)(cb + (size_t)k * DIM))[tid];
    ushort2 o; o.x = f2bf(v.x); o.y = f2bf(v.y);
    ((ushort2*)(cbb + (size_t)k * DIM))[tid] = o;
    float p = v.x * v.x + v.y * v.y;
    for (int m = 32; m; m >>= 1) p += __shfl_down(p, m, 64);
    if ((tid & 63) == 0) red[tid >> 6] = p;
    __syncthreads();
    if (tid == 0) enorm[k] = (red[0] + red[1]) + (red[2] + red[3]);
}

// ---- kernel 3: MFMA GEMM + argmin epilogue -----------------------------
__global__ __launch_bounds__(256, 2) void gemm_argmin(
    const unsigned short* __restrict__ zb, const unsigned short* __restrict__ cbb,
    const float* __restrict__ enorm, float* __restrict__ candV, int* __restrict__ candI) {
    __shared__ unsigned short As[BM * BK];   // 16 KB
    __shared__ unsigned short Bs[BN * BK];   // 16 KB
    __shared__ float Es[BN];
    __shared__ float cV[BM][2];
    __shared__ int cI[BM][2];

    const int tid = threadIdx.x;
    const int lane = tid & 63;
    const int w = tid >> 6;
    const int ktile = blockIdx.x;
    const int mtile = blockIdx.y;
    const int mbase = mtile * BM;
    const int nbase = ktile * BN;

    if (tid < BN) Es[tid] = enorm[nbase + tid];

    f32x4 acc[16];
#pragma unroll
    for (int i = 0; i < 16; ++i) acc[i] = (f32x4){0.f, 0.f, 0.f, 0.f};

    const int rA = lane >> 3;               // row offset within 8-row chunk
    const int jG = ((lane & 7) ^ rA) * 8;   // swizzled global 8-short chunk
    const int quad = lane >> 4;
    const int l15 = lane & 15;
    const int sw = (l15 & 7);               // read-side xor term = row&7
    const int rw = (w >> 1) * 64;           // wave's row quadrant
    const int cw = (w & 1) * 64;            // wave's col quadrant

    for (int dt = 0; dt < DIM; dt += BK) {
#pragma unroll
        for (int i = 0; i < 4; ++i) {
            int c = w * 4 + i;                       // 1KB chunk id (0..15)
            int row = c * 8 + rA;
            const unsigned short* ga = zb + (size_t)(mbase + row) * DIM + dt + jG;
            const unsigned short* gb = cbb + (size_t)(nbase + row) * DIM + dt + jG;
            unsigned short* la = As + c * 512 + lane * 8;
            unsigned short* lb = Bs + c * 512 + lane * 8;
            __builtin_amdgcn_global_load_lds((const __attribute__((address_space(1))) void*)ga,
                                             (__attribute__((address_space(3))) void*)la, 16, 0, 0);
            __builtin_amdgcn_global_load_lds((const __attribute__((address_space(1))) void*)gb,
                                             (__attribute__((address_space(3))) void*)lb, 16, 0, 0);
        }
        __syncthreads();
#pragma unroll
        for (int s = 0; s < 2; ++s) {
            // global chunk wanted: s*4 + quad; LDS chunk = (s*4+quad)^(row&7)
            const int jL = ((s * 4 + quad) ^ sw) * 8;
            bf16x8 af[4], bfr[4];
#pragma unroll
            for (int rf = 0; rf < 4; ++rf)
                af[rf] = *(const bf16x8*)(As + (rw + rf * 16 + l15) * BK + jL);
#pragma unroll
            for (int cf = 0; cf < 4; ++cf)
                bfr[cf] = *(const bf16x8*)(Bs + (cw + cf * 16 + l15) * BK + jL);
#pragma unroll
            for (int rf = 0; rf < 4; ++rf)
#pragma unroll
                for (int cf = 0; cf < 4; ++cf)
                    acc[rf * 4 + cf] = __builtin_amdgcn_mfma_f32_16x16x32_bf16(
                        af[rf], bfr[cf], acc[rf * 4 + cf], 0, 0, 0);
        }
        __syncthreads();
    }

    // epilogue: per-row argmin over this tile's 128 cols.
    // C/D layout: col = lane&15, row = quad*4 + reg.
#pragma unroll
    for (int rf = 0; rf < 4; ++rf) {
#pragma unroll
        for (int r = 0; r < 4; ++r) {
            float bv = 3.4e38f; int bi = 0x7fffffff;
#pragma unroll
            for (int cf = 0; cf < 4; ++cf) {
                int col = cw + cf * 16 + l15;
                float dist = Es[col] - 2.0f * acc[rf * 4 + cf][r];
                if (dist < bv) { bv = dist; bi = nbase + col; }  // strict <: lowest idx on tie
            }
#pragma unroll
            for (int m = 1; m < 16; m <<= 1) {
                float ov = __shfl_xor(bv, m, 64);
                int oi = __shfl_xor(bi, m, 64);
                if (ov < bv || (ov == bv && oi < bi)) { bv = ov; bi = oi; }
            }
            if (l15 == 0) {
                int rowT = rw + rf * 16 + quad * 4 + r;
                cV[rowT][w & 1] = bv;
                cI[rowT][w & 1] = bi;
            }
        }
    }
    __syncthreads();
    if (tid < BM) {
        float v0 = cV[tid][0], v1 = cV[tid][1];
        int i0 = cI[tid][0], i1 = cI[tid][1];
        bool take1 = (v1 < v0) || (v1 == v0 && i1 < i0);
        int row = mbase + tid;
        candV[(size_t)row * NT + ktile] = take1 ? v1 : v0;
        candI[(size_t)row * NT + ktile] = take1 ? i1 : i0;
    }
}

// ---- kernel 4: reduce 64 candidates per row -> final index -------------
__global__ __launch_bounds__(256) void reduce_cand(const float* __restrict__ candV,
                                                   const int* __restrict__ candI,
                                                   int* __restrict__ idxOut,
                                                   float* __restrict__ lossSlot) {
    int w = threadIdx.x >> 6, lane = threadIdx.x & 63;
    int row = blockIdx.x * 4 + w;
    float v = candV[(size_t)row * NT + lane];
    int i = candI[(size_t)row * NT + lane];
    for (int m = 1; m < 64; m <<= 1) {
        float ov = __shfl_xor(v, m, 64);
        int oi = __shfl_xor(i, m, 64);
        if (ov < v || (ov == v && oi < i)) { v = ov; i = oi; }
    }
    if (lane == 0) idxOut[row] = i;
    if (blockIdx.x == 0 && threadIdx.x == 0) *lossSlot = 0.f;  // k5 (next launch) accumulates
}

// ---- kernel 5: gather, straight-through output, loss -------------------
// Grid-stride: 1024 blocks, 2 rows per block-iter (128 lanes x float4 per
// row), 8 iters. Loss accumulated in registers; ONE atomic per block.
__global__ __launch_bounds__(256) void gather_out(const float* __restrict__ z,
                                                  const float* __restrict__ cb,
                                                  const int* __restrict__ idx,
                                                  float* __restrict__ out) {
    __shared__ float red[4];
    const int tid = threadIdx.x;
    const int sub = tid & 127;     // float4 slot within row
    const int rsub = tid >> 7;     // 0/1: which row of the pair
    float lsum = 0.f;
#pragma unroll
    for (int it = 0; it < M_ROWS / (GB_BLOCKS * 2); ++it) {
        int row = (it * GB_BLOCKS + blockIdx.x) * 2 + rsub;
        int k = idx[row];
        float4 zv = ((const float4*)(z + (size_t)row * DIM))[sub];
        float4 cv = ((const float4*)(cb + (size_t)k * DIM))[sub];
        float dx = cv.x - zv.x, dy = cv.y - zv.y;
        float dz2 = cv.z - zv.z, dw = cv.w - zv.w;
        float4 o = {zv.x + dx, zv.y + dy, zv.z + dz2, zv.w + dw};  // z + sg(zq-z)
        ((float4*)(out + (size_t)row * DIM))[sub] = o;
        lsum += dx * dx + dy * dy + dz2 * dz2 + dw * dw;
    }
    for (int m = 32; m; m >>= 1) lsum += __shfl_down(lsum, m, 64);
    if ((tid & 63) == 0) red[tid >> 6] = lsum;
    __syncthreads();
    if (tid == 0) {
        float t = (red[0] + red[1]) + (red[2] + red[3]);
        atomicAdd(out + OUT0_SIZE, t * (1.1f / (float)OUT0_SIZE));  // vq_loss = 1.1 * mean
    }
}

extern "C" void kernel_launch(void* const* d_in, const int* in_sizes, int n_in,
                              void* d_out, int out_size, void* d_ws, size_t ws_size,
                              hipStream_t stream) {
    const float* z = (const float*)d_in[0];     // 16*1024*512
    const float* cb = (const float*)d_in[1];    // 8192*512
    float* out = (float*)d_out;                 // 8388608 + 1
    char* ws = (char*)d_ws;

    // ws layout (bytes)
    unsigned short* zb  = (unsigned short*)(ws);              // 16,777,216
    unsigned short* cbb = (unsigned short*)(ws + 16777216);   //  8,388,608
    float* enorm        = (float*)(ws + 25165824);            //     32,768
    float* candV        = (float*)(ws + 25198592);            //  4,194,304
    int*   candI        = (int*)(ws + 29392896);              //  4,194,304
    int*   idxOut       = (int*)(ws + 33587200);              //     65,536

    convert_z<<<8192, 256, 0, stream>>>(z, zb);
    convert_cb<<<8192, 256, 0, stream>>>(cb, cbb, enorm);
    gemm_argmin<<<dim3(NT, M_ROWS / BM), 256, 0, stream>>>(zb, cbb, enorm, candV, candI);
    reduce_cand<<<M_ROWS / 4, 256, 0, stream>>>(candV, candI, idxOut, out + OUT0_SIZE);
    gather_out<<<GB_BLOCKS, 256, 0, stream>>>(z, cb, idxOut, out);
}